// Round 2
// baseline (890.636 us; speedup 1.0000x reference)
//
#include <hip/hip_runtime.h>

typedef __attribute__((ext_vector_type(8))) short short8;
typedef __attribute__((ext_vector_type(4))) float float4v;

#define NNODES 8192
#define SEQLEN 256

static __device__ __forceinline__ float bf2f(unsigned short u) {
  union { unsigned u; float f; } v; v.u = ((unsigned)u) << 16; return v.f;
}
static __device__ __forceinline__ unsigned short f2bf(float f) {
  union { float f; unsigned u; } v; v.f = f;
  unsigned r = v.u + 0x7FFFu + ((v.u >> 16) & 1u);
  return (unsigned short)(r >> 16);
}
static __device__ __forceinline__ float sigm(float x) {
  float e = __builtin_amdgcn_exp2f(-1.44269504089f * x);
  return __builtin_amdgcn_rcpf(1.f + e);
}
static __device__ __forceinline__ float tanh_(float x) {
  float e = __builtin_amdgcn_exp2f(2.88539008178f * fminf(x, 20.f));
  return (e - 1.f) * __builtin_amdgcn_rcpf(e + 1.f);
}
// split f32 -> bf16 hi + bf16 lo (v = hi + lo + O(2^-18 * v))
static __device__ __forceinline__ void split8(const float* v, short8& hi, short8& lo) {
#pragma unroll
  for (int j = 0; j < 8; ++j) {
    unsigned short h = f2bf(v[j]);
    hi[j] = (short)h;
    float r = v[j] - bf2f(h);
    lo[j] = (short)f2bf(r);
  }
}

// ---- fused 2-layer LSTM + LayerNorm; 16 nodes per wave; f32 via split-bf16 MFMA
__global__ __launch_bounds__(64, 1)
void lstm_fused(const float* __restrict__ x,
                const float* __restrict__ Wih1, const float* __restrict__ Whh1,
                const float* __restrict__ bih1, const float* __restrict__ bhh1,
                const float* __restrict__ ln_g, const float* __restrict__ ln_b,
                const float* __restrict__ Wih2, const float* __restrict__ Whh2,
                const float* __restrict__ bih2, const float* __restrict__ bhh2,
                float* __restrict__ h2out)
{
  const int lane = threadIdx.x;
  const int c = lane & 15;        // MFMA col (B n-index, A m-index, D col)
  const int q = lane >> 4;        // quad: K-group for A/B, row-group for D
  const int nodeBase = blockIdx.x * 16;

  // f32 transpose buffers, row stride 36 floats (144B: 16B-aligned rows)
  __shared__ __align__(16) float buf1[16 * 36];
  __shared__ __align__(16) float buf2[16 * 36];

  // B fragments (hi/lo): frag elem j = W[n = tn*16+c][k = q*8+j]
  short8 Bhh1h[8], Bhh1l[8], Bih2h[8], Bih2l[8], Bhh2h[8], Bhh2l[8];
  float b1v[8], b2v[8], w1v[8];
#pragma unroll
  for (int tn = 0; tn < 8; ++tn) {
    int n = tn * 16 + c;
    float w[8];
#pragma unroll
    for (int j = 0; j < 8; ++j) w[j] = Whh1[n * 32 + q * 8 + j];
    split8(w, Bhh1h[tn], Bhh1l[tn]);
#pragma unroll
    for (int j = 0; j < 8; ++j) w[j] = Wih2[n * 32 + q * 8 + j];
    split8(w, Bih2h[tn], Bih2l[tn]);
#pragma unroll
    for (int j = 0; j < 8; ++j) w[j] = Whh2[n * 32 + q * 8 + j];
    split8(w, Bhh2h[tn], Bhh2l[tn]);
    b1v[tn] = bih1[n] + bhh1[n];
    b2v[tn] = bih2[n] + bhh2[n];
    w1v[tn] = Wih1[n];            // Wih1 is (128,1)
  }
  float lngv[8], lnbv[8];
#pragma unroll
  for (int j = 0; j < 8; ++j) { lngv[j] = ln_g[q * 8 + j]; lnbv[j] = ln_b[q * 8 + j]; }

  short8 h1h = {0,0,0,0,0,0,0,0}, h1l = {0,0,0,0,0,0,0,0};
  short8 h2h = {0,0,0,0,0,0,0,0}, h2l = {0,0,0,0,0,0,0,0};
  float c1v[4][2] = {{0.f,0.f},{0.f,0.f},{0.f,0.f},{0.f,0.f}};
  float c2v[4][2] = {{0.f,0.f},{0.f,0.f},{0.f,0.f},{0.f,0.f}};
  const float4v z4 = {0.f, 0.f, 0.f, 0.f};
  const float* xp = x + (size_t)(nodeBase + q * 4) * SEQLEN;

  for (int t = 0; t < SEQLEN; ++t) {
    // layer1: z1 = h1 @ Whh1^T  (split product: hi*hi + hi*lo + lo*hi)
    float4v z1[8];
#pragma unroll
    for (int tn = 0; tn < 8; ++tn) {
      float4v a = __builtin_amdgcn_mfma_f32_16x16x32_bf16(h1l, Bhh1h[tn], z4, 0, 0, 0);
      a = __builtin_amdgcn_mfma_f32_16x16x32_bf16(h1h, Bhh1l[tn], a, 0, 0, 0);
      z1[tn] = __builtin_amdgcn_mfma_f32_16x16x32_bf16(h1h, Bhh1h[tn], a, 0, 0, 0);
    }
    float xr[4];
#pragma unroll
    for (int r = 0; r < 4; ++r) xr[r] = xp[r * SEQLEN + t];

    // cell: lane owns node = nodeBase+q*4+r, hh = c+16*jj (D: row=q*4+r, col=c)
#pragma unroll
    for (int r = 0; r < 4; ++r) {
#pragma unroll
      for (int jj = 0; jj < 2; ++jj) {
        float zi = z1[0+jj][r] + xr[r] * w1v[0+jj] + b1v[0+jj];
        float zf = z1[2+jj][r] + xr[r] * w1v[2+jj] + b1v[2+jj];
        float zg = z1[4+jj][r] + xr[r] * w1v[4+jj] + b1v[4+jj];
        float zo = z1[6+jj][r] + xr[r] * w1v[6+jj] + b1v[6+jj];
        float cn = sigm(zf) * c1v[r][jj] + sigm(zi) * tanh_(zg);
        c1v[r][jj] = cn;
        buf1[(q * 4 + r) * 36 + c + 16 * jj] = sigm(zo) * tanh_(cn);
      }
    }
    __syncthreads();
    // A layout: h1[m=c][k=q*8+j]
    float hvv[8];
#pragma unroll
    for (int j = 0; j < 8; ++j) hvv[j] = buf1[c * 36 + q * 8 + j];
    split8(hvv, h1h, h1l);

    // LayerNorm over the 32 hidden dims (8 local x 4 q-groups)
    float s = 0.f, s2 = 0.f;
#pragma unroll
    for (int j = 0; j < 8; ++j) { s += hvv[j]; s2 += hvv[j] * hvv[j]; }
    s  += __shfl_xor(s, 16, 64);  s  += __shfl_xor(s, 32, 64);
    s2 += __shfl_xor(s2, 16, 64); s2 += __shfl_xor(s2, 32, 64);
    float mu = s * (1.f / 32.f);
    float var = s2 * (1.f / 32.f) - mu * mu;
    float rstd = rsqrtf(var + 1e-5f);
    float yv[8];
#pragma unroll
    for (int j = 0; j < 8; ++j) yv[j] = (hvv[j] - mu) * rstd * lngv[j] + lnbv[j];
    short8 yh, yl;
    split8(yv, yh, yl);

    // layer2: z2 = y @ Wih2^T + h2 @ Whh2^T (each split into 3 MFMAs)
    float4v z2[8];
#pragma unroll
    for (int tn = 0; tn < 8; ++tn) {
      float4v a = __builtin_amdgcn_mfma_f32_16x16x32_bf16(yl, Bih2h[tn], z4, 0, 0, 0);
      a = __builtin_amdgcn_mfma_f32_16x16x32_bf16(yh, Bih2l[tn], a, 0, 0, 0);
      a = __builtin_amdgcn_mfma_f32_16x16x32_bf16(yh, Bih2h[tn], a, 0, 0, 0);
      a = __builtin_amdgcn_mfma_f32_16x16x32_bf16(h2l, Bhh2h[tn], a, 0, 0, 0);
      a = __builtin_amdgcn_mfma_f32_16x16x32_bf16(h2h, Bhh2l[tn], a, 0, 0, 0);
      z2[tn] = __builtin_amdgcn_mfma_f32_16x16x32_bf16(h2h, Bhh2h[tn], a, 0, 0, 0);
    }
#pragma unroll
    for (int r = 0; r < 4; ++r) {
#pragma unroll
      for (int jj = 0; jj < 2; ++jj) {
        float zi = z2[0+jj][r] + b2v[0+jj];
        float zf = z2[2+jj][r] + b2v[2+jj];
        float zg = z2[4+jj][r] + b2v[4+jj];
        float zo = z2[6+jj][r] + b2v[6+jj];
        float cn = sigm(zf) * c2v[r][jj] + sigm(zi) * tanh_(zg);
        c2v[r][jj] = cn;
        float hv = sigm(zo) * tanh_(cn);
        buf2[(q * 4 + r) * 36 + c + 16 * jj] = hv;
        if (t == SEQLEN - 1)
          h2out[(size_t)(nodeBase + q * 4 + r) * 32 + c + 16 * jj] = hv;
      }
    }
    __syncthreads();
    float h2vv[8];
#pragma unroll
    for (int j = 0; j < 8; ++j) h2vv[j] = buf2[c * 36 + q * 8 + j];
    split8(h2vv, h2h, h2l);
  }
}

// ---------------- GCN (all f32) ----------------
__global__ void deg_init(float* __restrict__ deg) {
  int i = blockIdx.x * 256 + threadIdx.x;
  if (i < NNODES) deg[i] = 1.f;
}
__global__ void deg_acc(const int* __restrict__ ei, const float* __restrict__ ew,
                        float* __restrict__ deg, int E) {
  int e = blockIdx.x * 256 + threadIdx.x;
  if (e < E) atomicAdd(&deg[ei[E + e]], ew[e]);
}
__global__ void gcn_mm1(const float* __restrict__ h2, const float* __restrict__ Wg1,
                        const float* __restrict__ deg, float* __restrict__ dinv,
                        float* __restrict__ hW, float* __restrict__ agg) {
  __shared__ float wg[32 * 33];
  int tid = threadIdx.x;
  for (int i = tid; i < 1024; i += 256) wg[(i >> 5) * 33 + (i & 31)] = Wg1[i];
  __syncthreads();
  int nl = tid >> 5, j = tid & 31;
  int node = blockIdx.x * 8 + nl;
  const float* hr = h2 + (size_t)node * 32;
  float acc = 0.f;
#pragma unroll
  for (int k = 0; k < 32; ++k) acc = fmaf(hr[k], wg[k * 33 + j], acc);
  float dv = rsqrtf(deg[node]);
  if (j == 0) dinv[node] = dv;
  hW[(size_t)node * 32 + j] = acc;
  agg[(size_t)node * 32 + j] = acc * dv * dv;
}
__global__ void gcn_edge(const int* __restrict__ ei, const float* __restrict__ ew,
                         const float* __restrict__ dinv, const float* __restrict__ hW,
                         float* __restrict__ agg, int E) {
  int gid = blockIdx.x * 256 + threadIdx.x;
  int e = gid >> 5, j = gid & 31;
  if (e >= E) return;
  int s = ei[e], d = ei[E + e];
  float coeff = dinv[s] * ew[e] * dinv[d];
  atomicAdd(&agg[(size_t)d * 32 + j], coeff * hW[(size_t)s * 32 + j]);
}
__global__ void gcn_mid(const float* __restrict__ bg1, const float* __restrict__ Wg2,
                        const float* __restrict__ dinv,
                        float* __restrict__ hW, float* __restrict__ agg) {
  __shared__ float wg[32 * 33];
  __shared__ float g1buf[8][33];
  int tid = threadIdx.x;
  for (int i = tid; i < 1024; i += 256) wg[(i >> 5) * 33 + (i & 31)] = Wg2[i];
  int nl = tid >> 5, j = tid & 31;
  int node = blockIdx.x * 8 + nl;
  float v = agg[(size_t)node * 32 + j] + bg1[j];
  g1buf[nl][j] = (v > 0.f) ? v : expm1f(v);
  __syncthreads();
  float acc = 0.f;
#pragma unroll
  for (int k = 0; k < 32; ++k) acc = fmaf(g1buf[nl][k], wg[k * 33 + j], acc);
  float dv = dinv[node];
  hW[(size_t)node * 32 + j] = acc;
  agg[(size_t)node * 32 + j] = acc * dv * dv;
}
__global__ void final_k(const float* __restrict__ h2, const float* __restrict__ agg,
                        const float* __restrict__ bg2, const float* __restrict__ Wfc,
                        const float* __restrict__ bfc, float* __restrict__ out) {
  int node = blockIdx.x * 256 + threadIdx.x;
  if (node >= NNODES) return;
  const float* ar = agg + (size_t)node * 32;
  float msum = 0.f;
#pragma unroll
  for (int k = 0; k < 32; ++k) {
    float v = ar[k] + bg2[k];
    msum += (v > 0.f) ? v : expm1f(v);
  }
  float mean = msum * (1.f / 32.f);
  const float* hr = h2 + (size_t)node * 32;
  float o0 = bfc[0], o1 = bfc[1];
#pragma unroll
  for (int k = 0; k < 32; ++k) {
    float hv = hr[k];
    o0 = fmaf(hv, Wfc[k], o0);
    o1 = fmaf(hv, Wfc[33 + k], o1);
  }
  o0 = fmaf(mean, Wfc[32], o0);
  o1 = fmaf(mean, Wfc[65], o1);
  float m = fmaxf(o0, o1);
  float l = m + logf(expf(o0 - m) + expf(o1 - m));
  out[node * 2 + 0] = o0 - l;
  out[node * 2 + 1] = o1 - l;
}

extern "C" void kernel_launch(void* const* d_in, const int* in_sizes, int n_in,
                              void* d_out, int out_size, void* d_ws, size_t ws_size,
                              hipStream_t stream) {
  const float* x    = (const float*)d_in[0];
  const float* ew   = (const float*)d_in[1];
  const float* Wih1 = (const float*)d_in[2];
  const float* Whh1 = (const float*)d_in[3];
  const float* bih1 = (const float*)d_in[4];
  const float* bhh1 = (const float*)d_in[5];
  const float* ln_g = (const float*)d_in[6];
  const float* ln_b = (const float*)d_in[7];
  const float* Wih2 = (const float*)d_in[8];
  const float* Whh2 = (const float*)d_in[9];
  const float* bih2 = (const float*)d_in[10];
  const float* bhh2 = (const float*)d_in[11];
  const float* Wg1  = (const float*)d_in[12];
  const float* bg1  = (const float*)d_in[13];
  const float* Wg2  = (const float*)d_in[14];
  const float* bg2  = (const float*)d_in[15];
  const float* Wfc  = (const float*)d_in[16];
  const float* bfc  = (const float*)d_in[17];
  const int* ei     = (const int*)d_in[18];
  float* out = (float*)d_out;
  const int E = in_sizes[1];   // 262144

  float* ws   = (float*)d_ws;
  float* h2   = ws;                 // 262144
  float* hW   = ws + 262144;        // 262144
  float* agg  = ws + 524288;        // 262144
  float* deg  = ws + 786432;        // 8192
  float* dinv = ws + 794624;        // 8192

  hipLaunchKernelGGL(deg_init, dim3(32), dim3(256), 0, stream, deg);
  hipLaunchKernelGGL(deg_acc, dim3((E + 255) / 256), dim3(256), 0, stream, ei, ew, deg, E);
  hipLaunchKernelGGL(lstm_fused, dim3(NNODES / 16), dim3(64), 0, stream,
                     x, Wih1, Whh1, bih1, bhh1, ln_g, ln_b,
                     Wih2, Whh2, bih2, bhh2, h2);
  hipLaunchKernelGGL(gcn_mm1, dim3(NNODES / 8), dim3(256), 0, stream, h2, Wg1, deg, dinv, hW, agg);
  hipLaunchKernelGGL(gcn_edge, dim3((E * 32 + 255) / 256), dim3(256), 0, stream, ei, ew, dinv, hW, agg, E);
  hipLaunchKernelGGL(gcn_mid, dim3(NNODES / 8), dim3(256), 0, stream, bg1, Wg2, dinv, hW, agg);
  hipLaunchKernelGGL(gcn_edge, dim3((E * 32 + 255) / 256), dim3(256), 0, stream, ei, ew, dinv, hW, agg, E);
  hipLaunchKernelGGL(final_k, dim3(NNODES / 256), dim3(256), 0, stream, h2, agg, bg2, Wfc, bfc, out);
}

// Round 3
// 609.487 us; speedup vs baseline: 1.4613x; 1.4613x over previous
//
#include <hip/hip_runtime.h>

typedef __attribute__((ext_vector_type(8))) short short8;
typedef __attribute__((ext_vector_type(4))) float float4v;

#define NNODES 8192
#define SEQLEN 256

static __device__ __forceinline__ float bf2f(unsigned short u) {
  union { unsigned u; float f; } v; v.u = ((unsigned)u) << 16; return v.f;
}
static __device__ __forceinline__ unsigned short f2bf(float f) {
  union { float f; unsigned u; } v; v.f = f;
  unsigned r = v.u + 0x7FFFu + ((v.u >> 16) & 1u);
  return (unsigned short)(r >> 16);
}
static __device__ __forceinline__ float sigm(float x) {
  float e = __builtin_amdgcn_exp2f(-1.44269504089f * x);
  return __builtin_amdgcn_rcpf(1.f + e);
}
static __device__ __forceinline__ float tanh_(float x) {
  float e = __builtin_amdgcn_exp2f(2.88539008178f * fminf(x, 20.f));
  return (e - 1.f) * __builtin_amdgcn_rcpf(e + 1.f);
}
static __device__ __forceinline__ void split8(const float* v, short8& hi, short8& lo) {
#pragma unroll
  for (int j = 0; j < 8; ++j) {
    unsigned short h = f2bf(v[j]);
    hi[j] = (short)h;
    lo[j] = (short)f2bf(v[j] - bf2f(h));
  }
}

// 8 waves per 16-node group; wave w owns gate-tile tn=w.
// zbuf stride 260 f32; x stride 257; h planes stride 40 shorts. All <=2-way conflicts.
__global__ __launch_bounds__(512, 4)
void lstm_fused(const float* __restrict__ x,
                const float* __restrict__ Wih1, const float* __restrict__ Whh1,
                const float* __restrict__ bih1, const float* __restrict__ bhh1,
                const float* __restrict__ ln_g, const float* __restrict__ ln_b,
                const float* __restrict__ Wih2, const float* __restrict__ Whh2,
                const float* __restrict__ bih2, const float* __restrict__ bhh2,
                float* __restrict__ h2out)
{
  const int tid = threadIdx.x;
  const int w = tid >> 6;           // wave 0..7 = gate tile
  const int lane = tid & 63;
  const int c = lane & 15;          // MFMA col / A-row
  const int q = lane >> 4;          // quad
  const int n = c;                  // cell node (local)
  const int hh = w * 4 + q;         // cell hidden index 0..31
  const int nodeBase = blockIdx.x * 16;

  __shared__ float xlds[16 * 257];
  __shared__ float zbuf[16 * 260];
  __shared__ __align__(16) unsigned short hhi[16 * 40];
  __shared__ __align__(16) unsigned short hlo[16 * 40];
  __shared__ float mubuf[32];       // [node*2] = mu, [node*2+1] = rstd

  // ---- stage x tile: 16 nodes x 256 t ----
  for (int i = tid; i < 16 * 256; i += 512) {
    int nn = i >> 8, tt = i & 255;
    xlds[nn * 257 + tt] = x[(size_t)(nodeBase + nn) * SEQLEN + tt];
  }

  // ---- B fragments for tile w: global gate rows w*16+c ----
  short8 Bh1h, Bh1l, Bi2h, Bi2l, Bh2h, Bh2l;
  {
    int row = w * 16 + c;
    float v[8];
#pragma unroll
    for (int j = 0; j < 8; ++j) v[j] = Whh1[row * 32 + q * 8 + j];
    split8(v, Bh1h, Bh1l);
#pragma unroll
    for (int j = 0; j < 8; ++j) v[j] = Wih2[row * 32 + q * 8 + j] * ln_g[q * 8 + j];
    split8(v, Bi2h, Bi2l);
#pragma unroll
    for (int j = 0; j < 8; ++j) v[j] = Whh2[row * 32 + q * 8 + j];
    split8(v, Bh2h, Bh2l);
  }
  // ---- cell constants: gate rows g*32+hh (g = i,f,g,o) ----
  float w1v[4], b1v[4], Gv[4], b2v[4];
#pragma unroll
  for (int g = 0; g < 4; ++g) {
    int row = g * 32 + hh;
    w1v[g] = Wih1[row];
    b1v[g] = bih1[row] + bhh1[row];
    float sG = 0.f, sB = 0.f;
    for (int k = 0; k < 32; ++k) {
      float wv = Wih2[row * 32 + k];
      sG += wv * ln_g[k];
      sB += wv * ln_b[k];
    }
    Gv[g] = sG;
    b2v[g] = sB + bih2[row] + bhh2[row];
  }

  short8 h1h = {0,0,0,0,0,0,0,0}, h1l = {0,0,0,0,0,0,0,0};
  short8 h2h = {0,0,0,0,0,0,0,0}, h2l = {0,0,0,0,0,0,0,0};
  float c1 = 0.f, c2 = 0.f;
  const float4v z4 = {0.f, 0.f, 0.f, 0.f};
  __syncthreads();

  for (int t = 0; t < SEQLEN; ++t) {
    // ---- layer1: z1 = h1 @ Whh1^T, tile w (split: 3 MFMAs) ----
    float4v za = __builtin_amdgcn_mfma_f32_16x16x32_bf16(h1l, Bh1h, z4, 0, 0, 0);
    za = __builtin_amdgcn_mfma_f32_16x16x32_bf16(h1h, Bh1l, za, 0, 0, 0);
    za = __builtin_amdgcn_mfma_f32_16x16x32_bf16(h1h, Bh1h, za, 0, 0, 0);
#pragma unroll
    for (int r = 0; r < 4; ++r)
      zbuf[(q * 4 + r) * 260 + w * 16 + c] = za[r];   // D: row=q*4+r, col=c
    __syncthreads();                                   // A

    // ---- cell layer1 (1 cell/lane) ----
    {
      float xv = xlds[n * 257 + t];
      float zi = zbuf[n * 260 +  0 + hh] + xv * w1v[0] + b1v[0];
      float zf = zbuf[n * 260 + 32 + hh] + xv * w1v[1] + b1v[1];
      float zg = zbuf[n * 260 + 64 + hh] + xv * w1v[2] + b1v[2];
      float zo = zbuf[n * 260 + 96 + hh] + xv * w1v[3] + b1v[3];
      c1 = sigm(zf) * c1 + sigm(zi) * tanh_(zg);
      float hv = sigm(zo) * tanh_(c1);
      unsigned short hi = f2bf(hv);
      hhi[n * 40 + hh] = hi;
      hlo[n * 40 + hh] = f2bf(hv - bf2f(hi));
    }
    __syncthreads();                                   // B

    h1h = *(const short8*)&hhi[c * 40 + q * 8];
    h1l = *(const short8*)&hlo[c * 40 + q * 8];
    if (w == 0) {      // wave 0 computes LN stats for all 16 nodes
      float s = 0.f, s2 = 0.f;
#pragma unroll
      for (int j = 0; j < 8; ++j) {
        float hv = bf2f((unsigned short)h1h[j]) + bf2f((unsigned short)h1l[j]);
        s += hv; s2 += hv * hv;
      }
      s  += __shfl_xor(s, 16, 64);  s  += __shfl_xor(s, 32, 64);
      s2 += __shfl_xor(s2, 16, 64); s2 += __shfl_xor(s2, 32, 64);
      float mu = s * (1.f / 32.f);
      float var = s2 * (1.f / 32.f) - mu * mu;
      float rstd = rsqrtf(var + 1e-5f);
      if (q == 0) { mubuf[c * 2] = mu; mubuf[c * 2 + 1] = rstd; }
    }

    // ---- layer2: Da = h1 @ (Wih2 . g)^T ; Db = h2 @ Whh2^T ----
    float4v da = __builtin_amdgcn_mfma_f32_16x16x32_bf16(h1l, Bi2h, z4, 0, 0, 0);
    da = __builtin_amdgcn_mfma_f32_16x16x32_bf16(h1h, Bi2l, da, 0, 0, 0);
    da = __builtin_amdgcn_mfma_f32_16x16x32_bf16(h1h, Bi2h, da, 0, 0, 0);
    float4v db = __builtin_amdgcn_mfma_f32_16x16x32_bf16(h2l, Bh2h, z4, 0, 0, 0);
    db = __builtin_amdgcn_mfma_f32_16x16x32_bf16(h2h, Bh2l, db, 0, 0, 0);
    db = __builtin_amdgcn_mfma_f32_16x16x32_bf16(h2h, Bh2h, db, 0, 0, 0);
#pragma unroll
    for (int r = 0; r < 4; ++r) {
      zbuf[(q * 4 + r) * 260 + w * 16 + c] = da[r];
      zbuf[(q * 4 + r) * 260 + 128 + w * 16 + c] = db[r];
    }
    __syncthreads();                                   // C

    // ---- cell layer2: z = rstd*(Da - mu*G) + Db + b2 ----
    {
      float mu = mubuf[n * 2], rstd = mubuf[n * 2 + 1];
      float zi = rstd * (zbuf[n * 260 +  0 + hh] - mu * Gv[0]) + zbuf[n * 260 + 128 +  0 + hh] + b2v[0];
      float zf = rstd * (zbuf[n * 260 + 32 + hh] - mu * Gv[1]) + zbuf[n * 260 + 128 + 32 + hh] + b2v[1];
      float zg = rstd * (zbuf[n * 260 + 64 + hh] - mu * Gv[2]) + zbuf[n * 260 + 128 + 64 + hh] + b2v[2];
      float zo = rstd * (zbuf[n * 260 + 96 + hh] - mu * Gv[3]) + zbuf[n * 260 + 128 + 96 + hh] + b2v[3];
      c2 = sigm(zf) * c2 + sigm(zi) * tanh_(zg);
      float hv = sigm(zo) * tanh_(c2);
      unsigned short hi = f2bf(hv);
      hhi[n * 40 + hh] = hi;
      hlo[n * 40 + hh] = f2bf(hv - bf2f(hi));
      if (t == SEQLEN - 1)
        h2out[(size_t)(nodeBase + n) * 32 + hh] = hv;
    }
    __syncthreads();                                   // D

    h2h = *(const short8*)&hhi[c * 40 + q * 8];
    h2l = *(const short8*)&hlo[c * 40 + q * 8];
  }
}

// ---------------- GCN (all f32) ----------------
__global__ void deg_init(float* __restrict__ deg) {
  int i = blockIdx.x * 256 + threadIdx.x;
  if (i < NNODES) deg[i] = 1.f;
}
__global__ void deg_acc(const int* __restrict__ ei, const float* __restrict__ ew,
                        float* __restrict__ deg, int E) {
  int e = blockIdx.x * 256 + threadIdx.x;
  if (e < E) atomicAdd(&deg[ei[E + e]], ew[e]);
}
__global__ void gcn_mm1(const float* __restrict__ h2, const float* __restrict__ Wg1,
                        const float* __restrict__ deg, float* __restrict__ dinv,
                        float* __restrict__ hW, float* __restrict__ agg) {
  __shared__ float wg[32 * 33];
  int tid = threadIdx.x;
  for (int i = tid; i < 1024; i += 256) wg[(i >> 5) * 33 + (i & 31)] = Wg1[i];
  __syncthreads();
  int nl = tid >> 5, j = tid & 31;
  int node = blockIdx.x * 8 + nl;
  const float* hr = h2 + (size_t)node * 32;
  float acc = 0.f;
#pragma unroll
  for (int k = 0; k < 32; ++k) acc = fmaf(hr[k], wg[k * 33 + j], acc);
  float dv = rsqrtf(deg[node]);
  if (j == 0) dinv[node] = dv;
  hW[(size_t)node * 32 + j] = acc;
  agg[(size_t)node * 32 + j] = acc * dv * dv;
}
__global__ void gcn_edge(const int* __restrict__ ei, const float* __restrict__ ew,
                         const float* __restrict__ dinv, const float* __restrict__ hW,
                         float* __restrict__ agg, int E) {
  int gid = blockIdx.x * 256 + threadIdx.x;
  int e = gid >> 5, j = gid & 31;
  if (e >= E) return;
  int s = ei[e], d = ei[E + e];
  float coeff = dinv[s] * ew[e] * dinv[d];
  atomicAdd(&agg[(size_t)d * 32 + j], coeff * hW[(size_t)s * 32 + j]);
}
__global__ void gcn_mid(const float* __restrict__ bg1, const float* __restrict__ Wg2,
                        const float* __restrict__ dinv,
                        float* __restrict__ hW, float* __restrict__ agg) {
  __shared__ float wg[32 * 33];
  __shared__ float g1buf[8][33];
  int tid = threadIdx.x;
  for (int i = tid; i < 1024; i += 256) wg[(i >> 5) * 33 + (i & 31)] = Wg2[i];
  int nl = tid >> 5, j = tid & 31;
  int node = blockIdx.x * 8 + nl;
  float v = agg[(size_t)node * 32 + j] + bg1[j];
  g1buf[nl][j] = (v > 0.f) ? v : expm1f(v);
  __syncthreads();
  float acc = 0.f;
#pragma unroll
  for (int k = 0; k < 32; ++k) acc = fmaf(g1buf[nl][k], wg[k * 33 + j], acc);
  float dv = dinv[node];
  hW[(size_t)node * 32 + j] = acc;
  agg[(size_t)node * 32 + j] = acc * dv * dv;
}
__global__ void final_k(const float* __restrict__ h2, const float* __restrict__ agg,
                        const float* __restrict__ bg2, const float* __restrict__ Wfc,
                        const float* __restrict__ bfc, float* __restrict__ out) {
  int node = blockIdx.x * 256 + threadIdx.x;
  if (node >= NNODES) return;
  const float* ar = agg + (size_t)node * 32;
  float msum = 0.f;
#pragma unroll
  for (int k = 0; k < 32; ++k) {
    float v = ar[k] + bg2[k];
    msum += (v > 0.f) ? v : expm1f(v);
  }
  float mean = msum * (1.f / 32.f);
  const float* hr = h2 + (size_t)node * 32;
  float o0 = bfc[0], o1 = bfc[1];
#pragma unroll
  for (int k = 0; k < 32; ++k) {
    float hv = hr[k];
    o0 = fmaf(hv, Wfc[k], o0);
    o1 = fmaf(hv, Wfc[33 + k], o1);
  }
  o0 = fmaf(mean, Wfc[32], o0);
  o1 = fmaf(mean, Wfc[65], o1);
  float m = fmaxf(o0, o1);
  float l = m + logf(expf(o0 - m) + expf(o1 - m));
  out[node * 2 + 0] = o0 - l;
  out[node * 2 + 1] = o1 - l;
}

extern "C" void kernel_launch(void* const* d_in, const int* in_sizes, int n_in,
                              void* d_out, int out_size, void* d_ws, size_t ws_size,
                              hipStream_t stream) {
  const float* x    = (const float*)d_in[0];
  const float* ew   = (const float*)d_in[1];
  const float* Wih1 = (const float*)d_in[2];
  const float* Whh1 = (const float*)d_in[3];
  const float* bih1 = (const float*)d_in[4];
  const float* bhh1 = (const float*)d_in[5];
  const float* ln_g = (const float*)d_in[6];
  const float* ln_b = (const float*)d_in[7];
  const float* Wih2 = (const float*)d_in[8];
  const float* Whh2 = (const float*)d_in[9];
  const float* bih2 = (const float*)d_in[10];
  const float* bhh2 = (const float*)d_in[11];
  const float* Wg1  = (const float*)d_in[12];
  const float* bg1  = (const float*)d_in[13];
  const float* Wg2  = (const float*)d_in[14];
  const float* bg2  = (const float*)d_in[15];
  const float* Wfc  = (const float*)d_in[16];
  const float* bfc  = (const float*)d_in[17];
  const int* ei     = (const int*)d_in[18];
  float* out = (float*)d_out;
  const int E = in_sizes[1];

  float* ws   = (float*)d_ws;
  float* h2   = ws;
  float* hW   = ws + 262144;
  float* agg  = ws + 524288;
  float* deg  = ws + 786432;
  float* dinv = ws + 794624;

  hipLaunchKernelGGL(deg_init, dim3(32), dim3(256), 0, stream, deg);
  hipLaunchKernelGGL(deg_acc, dim3((E + 255) / 256), dim3(256), 0, stream, ei, ew, deg, E);
  hipLaunchKernelGGL(lstm_fused, dim3(NNODES / 16), dim3(512), 0, stream,
                     x, Wih1, Whh1, bih1, bhh1, ln_g, ln_b,
                     Wih2, Whh2, bih2, bhh2, h2);
  hipLaunchKernelGGL(gcn_mm1, dim3(NNODES / 8), dim3(256), 0, stream, h2, Wg1, deg, dinv, hW, agg);
  hipLaunchKernelGGL(gcn_edge, dim3((E * 32 + 255) / 256), dim3(256), 0, stream, ei, ew, dinv, hW, agg, E);
  hipLaunchKernelGGL(gcn_mid, dim3(NNODES / 8), dim3(256), 0, stream, bg1, Wg2, dinv, hW, agg);
  hipLaunchKernelGGL(gcn_edge, dim3((E * 32 + 255) / 256), dim3(256), 0, stream, ei, ew, dinv, hW, agg, E);
  hipLaunchKernelGGL(final_k, dim3(NNODES / 256), dim3(256), 0, stream, h2, agg, bg2, Wfc, bfc, out);
}